// Round 1
// baseline (198.760 us; speedup 1.0000x reference)
//
#include <hip/hip_runtime.h>
#include <hip/hip_bf16.h>

// Problem constants
#define BATCH 1024
#define SEQ   336
#define CCH   64      // channels
#define ORD   168     // order (K)
#define TT    96      // tar_seq (N)
#define OFF   168     // SEQ - ORD

// Tile config
#define MB  16        // batches per block
#define NT  16        // t per block
#define KO  8         // o chunk
#define NCH (ORD/KO)  // 21 chunks
#define WSTRIDE (KO*NT + 1)  // 129: bank = c%32 for [c][.] layout -> conflict-free reads

__global__ __launch_bounds__(256, 2)
void tcl_lr_kernel(const float* __restrict__ inp,   // [B][SEQ][C]
                   const float* __restrict__ W,     // [C][ORD][T]
                   const float* __restrict__ bias,  // [C][T]
                   float* __restrict__ out)         // [B][T][C]
{
    __shared__ float Xs[MB * KO * CCH];      // [bi][oi][c]  32 KB
    __shared__ float Ws[CCH * WSTRIDE];      // [c][oi*NT+t] padded, ~33 KB

    const int tid = threadIdx.x;
    const int c   = tid & 63;        // lane = channel -> coalesced global I/O
    const int tg  = tid >> 6;        // 0..3 (t-group of 4)
    const int bblk = blockIdx.x / (TT / NT);   // 0..63
    const int tblk = blockIdx.x % (TT / NT);   // 0..5
    const int b0 = bblk * MB;
    const int t0 = tblk * NT;

    float acc[MB][4];
    #pragma unroll
    for (int bi = 0; bi < MB; ++bi)
        #pragma unroll
        for (int tj = 0; tj < 4; ++tj)
            acc[bi][tj] = 0.f;

    for (int ch = 0; ch < NCH; ++ch) {
        const int ob = ch * KO;

        // ---- stage X chunk: inputs[b0+bi][OFF+ob+oi][0..63] -> Xs[bi][oi][c]
        // 16*8*64 floats = 2048 float4, 8 per thread, fully coalesced.
        #pragma unroll
        for (int k = 0; k < 8; ++k) {
            int v   = tid + k * 256;       // 0..2047
            int row = v >> 4;              // bi*KO + oi, 0..127
            int c4  = v & 15;
            int bi  = row >> 3;
            int oi  = row & 7;
            const float4 x = *(const float4*)(inp +
                ((size_t)(b0 + bi) * SEQ + (OFF + ob + oi)) * CCH + c4 * 4);
            *(float4*)(Xs + row * CCH + c4 * 4) = x;
        }

        // ---- stage W chunk: W[cc][ob+oi][t0 + 0..15] -> Ws[cc][oi*16 + t]
        // 64*8*16 floats = 2048 float4 (over t), 8 per thread.
        #pragma unroll
        for (int k = 0; k < 8; ++k) {
            int v  = tid + k * 256;
            int cc = v >> 5;               // 0..63
            int oi = (v >> 2) & 7;         // 0..7
            int t4 = v & 3;                // 0..3
            const float4 w = *(const float4*)(W +
                (size_t)cc * (ORD * TT) + (size_t)(ob + oi) * TT + t0 + t4 * 4);
            float* d = Ws + cc * WSTRIDE + oi * NT + t4 * 4;
            d[0] = w.x; d[1] = w.y; d[2] = w.z; d[3] = w.w;
        }

        __syncthreads();

        // ---- compute: outer product 16b x 4t per thread per o
        #pragma unroll
        for (int oi = 0; oi < KO; ++oi) {
            float xv[MB];
            #pragma unroll
            for (int bi = 0; bi < MB; ++bi)
                xv[bi] = Xs[(bi * KO + oi) * CCH + c];
            float wv[4];
            #pragma unroll
            for (int tj = 0; tj < 4; ++tj)
                wv[tj] = Ws[c * WSTRIDE + oi * NT + tg * 4 + tj];
            #pragma unroll
            for (int bi = 0; bi < MB; ++bi)
                #pragma unroll
                for (int tj = 0; tj < 4; ++tj)
                    acc[bi][tj] += xv[bi] * wv[tj];
        }

        __syncthreads();
    }

    // ---- epilogue: bias + store (coalesced over c)
    float bv[4];
    #pragma unroll
    for (int tj = 0; tj < 4; ++tj)
        bv[tj] = bias[c * TT + t0 + tg * 4 + tj];

    #pragma unroll
    for (int bi = 0; bi < MB; ++bi)
        #pragma unroll
        for (int tj = 0; tj < 4; ++tj)
            out[((size_t)(b0 + bi) * TT + (t0 + tg * 4 + tj)) * CCH + c]
                = acc[bi][tj] + bv[tj];
}

extern "C" void kernel_launch(void* const* d_in, const int* in_sizes, int n_in,
                              void* d_out, int out_size, void* d_ws, size_t ws_size,
                              hipStream_t stream) {
    const float* inp  = (const float*)d_in[0];   // [1024][336][64]
    const float* W    = (const float*)d_in[1];   // [64][168][96]
    const float* bias = (const float*)d_in[2];   // [64][96]
    // d_in[3] = training flag, unused
    float* out = (float*)d_out;                  // [1024][96][64]

    dim3 grid((BATCH / MB) * (TT / NT));         // 64 * 6 = 384 blocks
    dim3 block(256);
    tcl_lr_kernel<<<grid, block, 0, stream>>>(inp, W, bias, out);
}

// Round 2
// 187.970 us; speedup vs baseline: 1.0574x; 1.0574x over previous
//
#include <hip/hip_runtime.h>
#include <hip/hip_bf16.h>

// Problem constants
#define BATCH 1024
#define SEQ   336
#define CCH   64      // channels
#define ORD   168     // order (K)
#define TT    96      // tar_seq (N)
#define OFF   168     // SEQ - ORD

// Tile config
#define MB  8         // batches per block
#define NT  16        // t per block
#define KO  8         // o chunk
#define NCH (ORD/KO)  // 21 chunks
// 132 words: rows 16B-aligned (132%4==0) and 33 words/4-word-chunk == 1 mod 32
// -> bank-group rotates with c -> conflict-free b128 reads AND writes.
#define WSTRIDE 132

typedef __attribute__((address_space(3))) void* lds_ptr_t;
typedef const __attribute__((address_space(1))) void* gbl_ptr_t;

__global__ __launch_bounds__(256, 4)
void tcl_lr_kernel(const float* __restrict__ inp,   // [B][SEQ][C]
                   const float* __restrict__ W,     // [C][ORD][T]
                   const float* __restrict__ bias,  // [C][T]
                   float* __restrict__ out)         // [B][T][C]
{
    __shared__ float Xs[MB * KO * CCH];      // [bi*KO+oi][c]  16 KB
    __shared__ float Ws[CCH * WSTRIDE];      // [c][oi*NT+t] padded, 33.8 KB

    const int tid = threadIdx.x;
    const int c   = tid & 63;        // lane = channel -> coalesced global I/O
    const int tg  = tid >> 6;        // wave id = t-group of 4
    // XCD swizzle: blocks sharing a batch-tile (same bblk, 6 tblks) get
    // blockIdx congruent mod 8 -> same XCD -> X slice served from its L2.
    const int bblk = blockIdx.x & 127;         // 0..127
    const int tblk = blockIdx.x >> 7;          // 0..5
    const int b0 = bblk * MB;
    const int t0 = tblk * NT;

    float acc[MB][4];
    #pragma unroll
    for (int bi = 0; bi < MB; ++bi)
        #pragma unroll
        for (int tj = 0; tj < 4; ++tj)
            acc[bi][tj] = 0.f;

    for (int ch = 0; ch < NCH; ++ch) {
        const int ob = ch * KO;

        // ---- stage X chunk: inputs[b0+bi][OFF+ob+oi][0..63] -> Xs[bi*8+oi][c]
        // 8*8*64 floats = 1024 float4, 4 per thread. LDS offset = v*16 B is
        // linear in lane -> legal for global_load_lds (wave base + lane*16).
        #pragma unroll
        for (int k = 0; k < 4; ++k) {
            int v   = tid + k * 256;       // 0..1023
            int row = v >> 4;              // bi*KO + oi, 0..63
            int c4  = v & 15;
            int bi  = row >> 3;
            int oi  = row & 7;
            const float* gp = inp +
                ((size_t)(b0 + bi) * SEQ + (OFF + ob + oi)) * CCH + c4 * 4;
            __builtin_amdgcn_global_load_lds((gbl_ptr_t)gp,
                                             (lds_ptr_t)(Xs + v * 4),
                                             16, 0, 0);
        }

        // ---- stage W chunk: W[cc][ob+oi][t0 + 0..15] -> Ws[cc][oi*16 + t]
        // padded stride forbids global_load_lds -> VGPR roundtrip, b128 writes.
        float4 wbuf[8];
        #pragma unroll
        for (int k = 0; k < 8; ++k) {
            int v  = tid + k * 256;
            int cc = v >> 5;               // 0..63
            int oi = (v >> 2) & 7;         // 0..7
            int t4 = v & 3;                // 0..3
            wbuf[k] = *(const float4*)(W +
                (size_t)cc * (ORD * TT) + (size_t)(ob + oi) * TT + t0 + t4 * 4);
        }
        #pragma unroll
        for (int k = 0; k < 8; ++k) {
            int v  = tid + k * 256;
            int cc = v >> 5;
            int oi = (v >> 2) & 7;
            int t4 = v & 3;
            *(float4*)(Ws + cc * WSTRIDE + oi * NT + t4 * 4) = wbuf[k];
        }

        __syncthreads();   // also drains global_load_lds (vmcnt) per HIP semantics

        // ---- compute: outer product 8b x 4t per thread per o
        #pragma unroll
        for (int oi = 0; oi < KO; ++oi) {
            const float4 wv = *(const float4*)(Ws + c * WSTRIDE + oi * NT + tg * 4);
            float xv[MB];
            #pragma unroll
            for (int bi = 0; bi < MB; ++bi)
                xv[bi] = Xs[(bi * KO + oi) * CCH + c];   // bank = c%32, 2-way = free
            #pragma unroll
            for (int bi = 0; bi < MB; ++bi) {
                acc[bi][0] += xv[bi] * wv.x;
                acc[bi][1] += xv[bi] * wv.y;
                acc[bi][2] += xv[bi] * wv.z;
                acc[bi][3] += xv[bi] * wv.w;
            }
        }

        __syncthreads();
    }

    // ---- epilogue: bias + store (coalesced over c; 4 scalar wave-stores of 256B)
    const float4 bv = *(const float4*)(bias + c * TT + t0 + tg * 4);

    #pragma unroll
    for (int bi = 0; bi < MB; ++bi) {
        float r0 = acc[bi][0] + bv.x;
        float r1 = acc[bi][1] + bv.y;
        float r2 = acc[bi][2] + bv.z;
        float r3 = acc[bi][3] + bv.w;
        size_t base = ((size_t)(b0 + bi) * TT + (t0 + tg * 4)) * CCH + c;
        out[base]           = r0;
        out[base + CCH]     = r1;
        out[base + 2 * CCH] = r2;
        out[base + 3 * CCH] = r3;
    }
}

extern "C" void kernel_launch(void* const* d_in, const int* in_sizes, int n_in,
                              void* d_out, int out_size, void* d_ws, size_t ws_size,
                              hipStream_t stream) {
    const float* inp  = (const float*)d_in[0];   // [1024][336][64]
    const float* W    = (const float*)d_in[1];   // [64][168][96]
    const float* bias = (const float*)d_in[2];   // [64][96]
    // d_in[3] = training flag, unused
    float* out = (float*)d_out;                  // [1024][96][64]

    dim3 grid((BATCH / MB) * (TT / NT));         // 128 * 6 = 768 blocks = 3/CU
    dim3 block(256);
    tcl_lr_kernel<<<grid, block, 0, stream>>>(inp, W, bias, out);
}